// Round 13
// baseline (131.779 us; speedup 1.0000x reference)
//
#include <hip/hip_runtime.h>

// LNSNet forward, R12: budget finally closed (fill 42.6 + k1 38 + k2 21 +
// k3 8 + k4 14 + gaps). Fixes: (1) fc1-weight permutation was a stride-576B
// gather (1.18M uncoalesced L2 txns) -> LDS tile transpose, one block per
// fc1 row; (2) fc1 split-K 32->16 (K-chunk 576); (3) k4 reduce widened to
// 256x256 with 16-slab coalesced reads.
// Standing: no device-scope fences (R6/R9); no launch_bounds forcing (R10).

#define B 512
#define POS 676
#define ICP 36
#define P2SZ (64*12*12)
#define SCR 26

typedef unsigned short ushort_t;
typedef ushort_t ushort4v __attribute__((ext_vector_type(4)));
typedef short s16x8 __attribute__((ext_vector_type(8)));
typedef float f32x4 __attribute__((ext_vector_type(4)));
typedef float f32x2 __attribute__((ext_vector_type(2)));

__device__ __forceinline__ ushort_t f2bf(float f) {
    union { float f; unsigned u; } a; a.f = f;
    unsigned r = a.u + 0x7FFFu + ((a.u >> 16) & 1u);
    return (ushort_t)(r >> 16);
}
__device__ __forceinline__ float bf2f(ushort_t u) {
    union { unsigned u; float f; } a; a.u = ((unsigned)u) << 16;
    return a.f;
}

#define N_WR (64 * 9 * 32)
#define CONV1_BLOCKS 3328
#define WR_BLOCKS 72            // 18432 / 256
#define TR_BLOCKS 128           // one per fc1 output row

// ---------------- k1: conv1 + wr prep + fc1-W tile transpose ----------------
__global__ __launch_bounds__(256) void conv1_prep(const float* __restrict__ x,
                                                  const float* __restrict__ w,
                                                  const float* __restrict__ bias,
                                                  const float* __restrict__ c2w,
                                                  const float* __restrict__ f1w,
                                                  ushort_t* __restrict__ out,
                                                  ushort_t* __restrict__ wr,
                                                  ushort_t* __restrict__ wfb) {
    __shared__ float tr[64 * 145];   // 37,120 B; stride 145 dwords (odd) = conflict-free
    int blk = blockIdx.x;
    int tid = threadIdx.x;

    if (blk >= CONV1_BLOCKS + WR_BLOCKS) {
        // ---- fc1 W transpose: row n, (oc,pos) -> k' = pos*64+oc, via LDS ----
        int n = blk - CONV1_BLOCKS - WR_BLOCKS;
        const float* src = f1w + (size_t)n * 9216;
#pragma unroll
        for (int i = 0; i < 36; ++i) {               // 36*256 = 9216 coalesced reads
            int idx = i * 256 + tid;
            int oc = idx / 144, pos = idx - oc * 144;
            tr[oc * 145 + pos] = src[idx];
        }
        __syncthreads();
        ushort_t* dst = wfb + (size_t)n * 9216;
#pragma unroll
        for (int i = 0; i < 36; ++i) {               // coalesced bf16 writes
            int idx = i * 256 + tid;                 // k' = pos*64 + oc
            int pos = idx >> 6, oc = idx & 63;
            dst[idx] = f2bf(tr[oc * 145 + pos]);
        }
        return;
    }
    if (blk >= CONV1_BLOCKS) {
        int t = (blk - CONV1_BLOCKS) * 256 + tid;    // conv2 weight reshuffle
        int ic  = t & 31;
        int tap = (t >> 5) % 9;
        int oc  = t / 288;
        wr[t] = f2bf(c2w[oc * 288 + ic * 9 + tap]);
        return;
    }
    // ---- conv1 sliding half-row, packed fp32 ----
    int t = blk * 256 + tid;
    int ic = t & 31;
    int r  = t >> 5;
    int h  = r & 1;
    int r2 = r >> 1;
    int py = r2 % 26;
    int b  = r2 / 26;
    int px0 = h * 13;

    const float* wp = w + ic * 9;
    float w00 = wp[0], w01 = wp[1], w02 = wp[2];
    float w10 = wp[3], w11 = wp[4], w12 = wp[5];
    float w20 = wp[6], w21 = wp[7], w22 = wp[8];
    float bv = bias[ic];

    const float* xr = x + b * (54 * 54) + (2 * py) * 54 + 2 * px0;
    ushort_t* po = out + ((size_t)b * POS + py * 26 + px0) * 32 + ic;

    f32x2 p[4], q[4];
#pragma unroll
    for (int rr = 0; rr < 4; ++rr) p[rr] = *reinterpret_cast<const f32x2*>(xr + rr * 54);
#pragma unroll
    for (int rr = 0; rr < 4; ++rr) q[rr] = *reinterpret_cast<const f32x2*>(xr + rr * 54 + 2);

#pragma unroll
    for (int j = 0; j < 13; ++j) {
        f32x2 mid[4];
#pragma unroll
        for (int rr = 0; rr < 4; ++rr) mid[rr] = (f32x2){p[rr].y, q[rr].x};

        f32x2 s0 = p[0] * (f32x2)w00 + mid[0] * (f32x2)w01 + q[0] * (f32x2)w02
                 + p[1] * (f32x2)w10 + mid[1] * (f32x2)w11 + q[1] * (f32x2)w12
                 + p[2] * (f32x2)w20 + mid[2] * (f32x2)w21 + q[2] * (f32x2)w22;
        f32x2 s1 = p[1] * (f32x2)w00 + mid[1] * (f32x2)w01 + q[1] * (f32x2)w02
                 + p[2] * (f32x2)w10 + mid[2] * (f32x2)w11 + q[2] * (f32x2)w12
                 + p[3] * (f32x2)w20 + mid[3] * (f32x2)w21 + q[3] * (f32x2)w22;

        float m = fmaxf(fmaxf(s0.x, s0.y), fmaxf(s1.x, s1.y));
        po[j * 32] = f2bf(fmaxf(m + bv, 0.0f));
        if (j < 12) {
#pragma unroll
            for (int rr = 0; rr < 4; ++rr) {
                p[rr] = q[rr];
                q[rr] = *reinterpret_cast<const f32x2*>(xr + rr * 54 + 2 * j + 4);
            }
        }
    }
}

// ---------------- k2: conv2 MFMA, 512-thr blocks (R11 form) ----------------
__global__ __launch_bounds__(512) void conv2_mfma(const ushort_t* __restrict__ p1,
                                                  const ushort_t* __restrict__ wr,
                                                  const float* __restrict__ bias,
                                                  ushort_t* __restrict__ pool2cl) {
    __shared__ ushort_t lds[260 * ICP];
    int blk = blockIdx.x;
    int b = blk / 3, c = blk % 3;
    int tid = threadIdx.x;

    const ushort_t* src = p1 + ((size_t)b * POS + 8 * c * 26) * 32;
    for (int t = tid; t < 260 * 8; t += 512) {
        int pos = t >> 3, off = (t & 7) * 4;
        ushort4v v = *reinterpret_cast<const ushort4v*>(src + pos * 32 + off);
        *reinterpret_cast<ushort4v*>(&lds[pos * ICP + off]) = v;
    }
    __syncthreads();

    int lane = tid & 63, wid = tid >> 6;
    int quad = lane >> 4, lr = lane & 15;
    int prow = wid >> 1;
    int nhalf = wid & 1;

    int ebase[3];
#pragma unroll
    for (int t = 0; t < 3; ++t) {
        int m  = t * 16 + lr;
        int yl = m / 24;
        int xx = m - yl * 24;
        ebase[t] = ((2 * prow + yl) * 26 + xx) * ICP + quad * 8;
    }

    f32x4 acc[3][2];
#pragma unroll
    for (int t = 0; t < 3; ++t)
#pragma unroll
        for (int n = 0; n < 2; ++n) acc[t][n] = (f32x4){0.f, 0.f, 0.f, 0.f};

    const ushort_t* wb = wr + (size_t)(nhalf * 32 + lr) * 288 + quad * 8;

#pragma unroll
    for (int tap = 0; tap < 9; ++tap) {
        int ky = tap / 3, kx = tap % 3;
        int koff = (ky * 26 + kx) * ICP;
        s16x8 a[3];
#pragma unroll
        for (int t = 0; t < 3; ++t) {
            union { ushort4v s[2]; s16x8 v; } u;
            u.s[0] = *reinterpret_cast<const ushort4v*>(&lds[ebase[t] + koff]);
            u.s[1] = *reinterpret_cast<const ushort4v*>(&lds[ebase[t] + koff + 4]);
            a[t] = u.v;
        }
        s16x8 bf[2];
#pragma unroll
        for (int n = 0; n < 2; ++n)
            bf[n] = *reinterpret_cast<const s16x8*>(wb + (size_t)n * 16 * 288 + tap * 32);
#pragma unroll
        for (int t = 0; t < 3; ++t)
#pragma unroll
            for (int n = 0; n < 2; ++n)
                acc[t][n] = __builtin_amdgcn_mfma_f32_16x16x32_bf16(a[t], bf[n], acc[t][n], 0, 0, 0);
    }
    __syncthreads();

    ushort_t* scr = lds + wid * (32 * SCR);
#pragma unroll
    for (int t = 0; t < 3; ++t)
#pragma unroll
        for (int n = 0; n < 2; ++n) {
            int ocl = n * 16 + lr;
            int i0 = t * 8 + quad * 2;
            float v0 = fmaxf(acc[t][n][0], acc[t][n][1]);
            float v1 = fmaxf(acc[t][n][2], acc[t][n][3]);
            union { ushort_t u2[2]; unsigned w; } pk;
            pk.u2[0] = f2bf(v0); pk.u2[1] = f2bf(v1);
            *reinterpret_cast<unsigned*>(&scr[ocl * SCR + i0]) = pk.w;
        }
    int ocl = lane & 31;
    int pxh = lane >> 5;
    int oc  = nhalf * 32 + ocl;
    const ushort_t* row = scr + ocl * SCR;
    float bv = bias[oc];
    int py = c * 4 + prow;
    ushort_t* po = pool2cl + ((size_t)b * 144 + py * 12) * 64 + oc;
#pragma unroll
    for (int j = 0; j < 6; ++j) {
        int px = pxh * 6 + j;
        float r0 = bf2f(row[px]);
        float r1 = bf2f(row[px + 12]);
        po[px * 64] = f2bf(fmaxf(fmaxf(r0, r1) + bv, 0.0f));
    }
}

// ---------------- k3: fc1 bf16 MFMA, 16 K-splits, 16m x 32n waves ----------------
// wave w = blk*4+wid: nt=w&3 (same mt,ks across block's 4 waves? no: nt varies,
// A-frag shared -> L1-hot). ks=(w>>2)&15 (K-chunk 576, 18 ksteps), mt=w>>6.
// 2048 waves = 512 blocks. Cpart[16][512][128].
__global__ __launch_bounds__(256) void fc1_mfma(const ushort_t* __restrict__ A,
                                                 const ushort_t* __restrict__ W,
                                                 float* __restrict__ Cpart) {
    int tid = threadIdx.x;
    int lane = tid & 63, wid = tid >> 6;
    int lr = lane & 15, quad = lane >> 4;
    int w  = blockIdx.x * 4 + wid;
    int nt = w & 3;
    int ks = (w >> 2) & 15;
    int mt = w >> 6;                 // 0..31

    int m0 = mt * 16;
    int n0 = nt * 32;
    int k0 = ks * 576 + quad * 8;
    const ushort_t* a0 = A + (size_t)(m0 + lr) * 9216 + k0;
    const ushort_t* b0 = W + (size_t)(n0 + lr) * 9216 + k0;
    const ushort_t* b1 = b0 + (size_t)16 * 9216;

    f32x4 acc0 = (f32x4){0.f, 0.f, 0.f, 0.f};
    f32x4 acc1 = (f32x4){0.f, 0.f, 0.f, 0.f};

#pragma unroll
    for (int kk = 0; kk < 18; ++kk) {
        s16x8 av  = *reinterpret_cast<const s16x8*>(a0 + kk * 32);
        s16x8 bv0 = *reinterpret_cast<const s16x8*>(b0 + kk * 32);
        s16x8 bv1 = *reinterpret_cast<const s16x8*>(b1 + kk * 32);
        acc0 = __builtin_amdgcn_mfma_f32_16x16x32_bf16(av, bv0, acc0, 0, 0, 0);
        acc1 = __builtin_amdgcn_mfma_f32_16x16x32_bf16(av, bv1, acc1, 0, 0, 0);
    }

    float* cp = Cpart + (size_t)ks * (512 * 128);
    int crow = m0 + quad * 4;
#pragma unroll
    for (int r = 0; r < 4; ++r) {
        cp[(size_t)(crow + r) * 128 + n0 + lr]      = acc0[r];
        cp[(size_t)(crow + r) * 128 + n0 + 16 + lr] = acc1[r];
    }
}

// ---------------- k4: fc1 reduce(16) + bias + relu + fc2, 2 batches/block ----------------
__global__ __launch_bounds__(256) void fc1fc2(const float* __restrict__ Cpart,
                                              const float* __restrict__ b1,
                                              const float* __restrict__ w2,
                                              const float* __restrict__ b2,
                                              float* __restrict__ out) {
    __shared__ float h[2][128];
    int half = threadIdx.x >> 7;
    int k = threadIdx.x & 127;
    int b = blockIdx.x * 2 + half;
    float s = 0.f;
#pragma unroll
    for (int ks = 0; ks < 16; ++ks) s += Cpart[(size_t)ks * (512 * 128) + b * 128 + k];
    h[half][k] = fmaxf(s + b1[k], 0.0f);
    __syncthreads();
    if (k < 10) {
        const float* wp = w2 + k * 128;
        float acc = 0.f;
#pragma unroll 8
        for (int j = 0; j < 128; ++j) acc += h[half][j] * wp[j];
        out[b * 10 + k] = acc + b2[k];
    }
}

extern "C" void kernel_launch(void* const* d_in, const int* in_sizes, int n_in,
                              void* d_out, int out_size, void* d_ws, size_t ws_size,
                              hipStream_t stream) {
    const float* x       = (const float*)d_in[0];
    const float* conv1_w = (const float*)d_in[1];
    const float* conv1_b = (const float*)d_in[2];
    const float* conv2_w = (const float*)d_in[3];
    const float* conv2_b = (const float*)d_in[4];
    const float* fc1_w   = (const float*)d_in[5];
    const float* fc1_b   = (const float*)d_in[6];
    const float* fc2_w   = (const float*)d_in[7];
    const float* fc2_b   = (const float*)d_in[8];
    float* out = (float*)d_out;

    char* ws = (char*)d_ws;
    ushort_t* pool1 = (ushort_t*)ws;
    ws += (size_t)B * POS * 32 * sizeof(ushort_t);
    ushort_t* wr = (ushort_t*)ws;
    ws += N_WR * sizeof(ushort_t) + 128;
    ushort_t* wfb = (ushort_t*)ws;
    ws += (size_t)128 * 9216 * sizeof(ushort_t) + 128;
    ushort_t* pool2cl = (ushort_t*)ws;
    ws += (size_t)B * P2SZ * sizeof(ushort_t) + 128;
    float* Cpart = (float*)ws;
    ws += (size_t)16 * 512 * 128 * sizeof(float) + 128;

    conv1_prep<<<CONV1_BLOCKS + WR_BLOCKS + TR_BLOCKS, 256, 0, stream>>>(
        x, conv1_w, conv1_b, conv2_w, fc1_w, pool1, wr, wfb);
    conv2_mfma<<<B * 3, 512, 0, stream>>>(pool1, wr, conv2_b, pool2cl);
    fc1_mfma<<<512, 256, 0, stream>>>(pool2cl, wfb, Cpart);
    fc1fc2<<<256, 256, 0, stream>>>(Cpart, fc1_b, fc2_w, fc2_b, out);
}

// Round 14
// 127.623 us; speedup vs baseline: 1.0326x; 1.0326x over previous
//
#include <hip/hip_runtime.h>

// LNSNet forward, R13: conv1 moved to MFMA. conv1 = GEMM M=2704 pos, N=32 oc,
// K=9 taps padded to 32 (k = ky*8+kx; kx>=3 and ky=3 slots carry ZERO weights,
// so garbage A reads there are annihilated). A-frag = 2 aligned ds_read_b32
// from a dual-copy (col-shifted) bf16 LDS image, row stride 58 (29 dwords,
// odd -> bank-spread). 1024 blocks = 2 per image, 4 waves, ~13 pooled rows.
// k2 (conv2, R11 form), k3/k4 (R12 forms) unchanged.
// Standing: no device-scope fences (R6/R9); no launch_bounds forcing (R10).

#define B 512
#define POS 676
#define ICP 36
#define P2SZ (64*12*12)
#define SCR 26
#define IMS 58                  // LDS image row stride (ushorts), odd dwords
#define IMCOPY (54 * IMS)       // 3132 ushorts per copy

typedef unsigned short ushort_t;
typedef ushort_t ushort4v __attribute__((ext_vector_type(4)));
typedef short s16x8 __attribute__((ext_vector_type(8)));
typedef float f32x4 __attribute__((ext_vector_type(4)));

__device__ __forceinline__ ushort_t f2bf(float f) {
    union { float f; unsigned u; } a; a.f = f;
    unsigned r = a.u + 0x7FFFu + ((a.u >> 16) & 1u);
    return (ushort_t)(r >> 16);
}
__device__ __forceinline__ float bf2f(ushort_t u) {
    union { unsigned u; float f; } a; a.u = ((unsigned)u) << 16;
    return a.f;
}

#define N_WR (64 * 9 * 32)
#define CONV1_BLOCKS 1024       // 2 per image
#define WR_BLOCKS 72
#define TR_BLOCKS 128

// ---------------- k1: conv1 MFMA + wr prep + fc1-W transpose ----------------
__global__ __launch_bounds__(256) void conv1_prep(const float* __restrict__ x,
                                                  const float* __restrict__ w,
                                                  const float* __restrict__ bias,
                                                  const float* __restrict__ c2w,
                                                  const float* __restrict__ f1w,
                                                  ushort_t* __restrict__ out,
                                                  ushort_t* __restrict__ wr,
                                                  ushort_t* __restrict__ wfb) {
    __shared__ char smem[64 * 145 * 4];     // 37,120 B, aliased per branch
    int blk = blockIdx.x;
    int tid = threadIdx.x;

    if (blk >= CONV1_BLOCKS + WR_BLOCKS) {
        // ---- fc1 W transpose via LDS tile (R12 form) ----
        float* tr = reinterpret_cast<float*>(smem);   // 64 x 145
        int n = blk - CONV1_BLOCKS - WR_BLOCKS;
        const float* src = f1w + (size_t)n * 9216;
#pragma unroll
        for (int i = 0; i < 36; ++i) {
            int idx = i * 256 + tid;
            int oc = idx / 144, pos = idx - oc * 144;
            tr[oc * 145 + pos] = src[idx];
        }
        __syncthreads();
        ushort_t* dst = wfb + (size_t)n * 9216;
#pragma unroll
        for (int i = 0; i < 36; ++i) {
            int idx = i * 256 + tid;
            int pos = idx >> 6, oc = idx & 63;
            dst[idx] = f2bf(tr[oc * 145 + pos]);
        }
        return;
    }
    if (blk >= CONV1_BLOCKS) {
        int t = (blk - CONV1_BLOCKS) * 256 + tid;
        int ic  = t & 31;
        int tap = (t >> 5) % 9;
        int oc  = t / 288;
        wr[t] = f2bf(c2w[oc * 288 + ic * 9 + tap]);
        return;
    }

    // ================= conv1 via MFMA =================
    ushort_t* lds = reinterpret_cast<ushort_t*>(smem);   // 2 copies + pad = 12,656 B
    int b    = blk >> 1;
    int half = blk & 1;

    // ---- stage image b: fp32 -> bf16, copy0 natural, copy1 shifted left 1 col ----
    const float* xim = x + (size_t)b * 2916;
    for (int i = tid; i < 2916; i += 256) {
        int r = i / 54, c = i - r * 54;
        ushort_t v = f2bf(xim[i]);
        lds[r * IMS + c] = v;
        if (c > 0) lds[IMCOPY + r * IMS + c - 1] = v;
    }

    int lane = tid & 63, wid = tid >> 6;
    int quad = lane >> 4, lr = lane & 15;

    // ---- B-frags: w[oc][ky=quad][kx=0..2], zeros elsewhere (incl quad==3) ----
    s16x8 bfrag[2];
#pragma unroll
    for (int n = 0; n < 2; ++n) {
        union { ushort_t u[8]; s16x8 v; } bu;
#pragma unroll
        for (int j = 0; j < 8; ++j) bu.u[j] = 0;
        if (quad < 3) {
            const float* wp = w + (n * 16 + lr) * 9 + quad * 3;
            bu.u[0] = f2bf(wp[0]);
            bu.u[1] = f2bf(wp[1]);
            bu.u[2] = f2bf(wp[2]);
        }
        bfrag[n] = bu.v;
    }
    float bv0 = bias[lr], bv1 = bias[16 + lr];

    __syncthreads();

    // per-lane LDS column base: even lanes read copy0 at col x0+lr,
    // odd lanes read copy1 at col x0+lr-1 (both 4B-aligned)
    int cbase = (lr & 1) ? (IMCOPY + lr - 1) : lr;

    for (int py_l = wid; py_l < 13; py_l += 4) {
        int py = half * 13 + py_l;
        int y0 = 2 * py;
#pragma unroll
        for (int t = 0; t < 4; ++t) {
            int x0 = t * 16;
            // A-frags for conv rows y0, y0+1
            int off0 = cbase + x0 + (y0 + quad) * IMS;
            int off1 = off0 + IMS;
            union { unsigned d[4]; s16x8 v; } a0, a1;
            a0.d[0] = *reinterpret_cast<const unsigned*>(&lds[off0]);
            a0.d[1] = *reinterpret_cast<const unsigned*>(&lds[off0 + 2]);
            a0.d[2] = a0.d[0]; a0.d[3] = a0.d[1];     // k slots 4..7: zero-weighted
            a1.d[0] = *reinterpret_cast<const unsigned*>(&lds[off1]);
            a1.d[1] = *reinterpret_cast<const unsigned*>(&lds[off1 + 2]);
            a1.d[2] = a1.d[0]; a1.d[3] = a1.d[1];

            f32x4 cA0 = (f32x4){0.f,0.f,0.f,0.f}, cA1 = cA0, cB0 = cA0, cB1 = cA0;
            cA0 = __builtin_amdgcn_mfma_f32_16x16x32_bf16(a0.v, bfrag[0], cA0, 0, 0, 0);
            cA1 = __builtin_amdgcn_mfma_f32_16x16x32_bf16(a0.v, bfrag[1], cA1, 0, 0, 0);
            cB0 = __builtin_amdgcn_mfma_f32_16x16x32_bf16(a1.v, bfrag[0], cB0, 0, 0, 0);
            cB1 = __builtin_amdgcn_mfma_f32_16x16x32_bf16(a1.v, bfrag[1], cB1, 0, 0, 0);

            // pool 2x2: regs (0,1) and (2,3) pair adjacent conv cols; y via cA/cB max
            if (t < 3 || quad == 0) {
                int px0 = t * 8 + quad * 2;
                float u0 = fmaxf(fmaxf(cA0[0], cA0[1]), fmaxf(cB0[0], cB0[1]));
                float u1 = fmaxf(fmaxf(cA0[2], cA0[3]), fmaxf(cB0[2], cB0[3]));
                float v0 = fmaxf(fmaxf(cA1[0], cA1[1]), fmaxf(cB1[0], cB1[1]));
                float v1 = fmaxf(fmaxf(cA1[2], cA1[3]), fmaxf(cB1[2], cB1[3]));
                ushort_t* po = out + ((size_t)b * POS + py * 26 + px0) * 32;
                po[lr]           = f2bf(fmaxf(u0 + bv0, 0.0f));
                po[32 + lr]      = f2bf(fmaxf(u1 + bv0, 0.0f));
                po[16 + lr]      = f2bf(fmaxf(v0 + bv1, 0.0f));
                po[32 + 16 + lr] = f2bf(fmaxf(v1 + bv1, 0.0f));
            }
        }
    }
}

// ---------------- k2: conv2 MFMA, 512-thr blocks (R11 form) ----------------
__global__ __launch_bounds__(512) void conv2_mfma(const ushort_t* __restrict__ p1,
                                                  const ushort_t* __restrict__ wr,
                                                  const float* __restrict__ bias,
                                                  ushort_t* __restrict__ pool2cl) {
    __shared__ ushort_t lds[260 * ICP];
    int blk = blockIdx.x;
    int b = blk / 3, c = blk % 3;
    int tid = threadIdx.x;

    const ushort_t* src = p1 + ((size_t)b * POS + 8 * c * 26) * 32;
    for (int t = tid; t < 260 * 8; t += 512) {
        int pos = t >> 3, off = (t & 7) * 4;
        ushort4v v = *reinterpret_cast<const ushort4v*>(src + pos * 32 + off);
        *reinterpret_cast<ushort4v*>(&lds[pos * ICP + off]) = v;
    }
    __syncthreads();

    int lane = tid & 63, wid = tid >> 6;
    int quad = lane >> 4, lr = lane & 15;
    int prow = wid >> 1;
    int nhalf = wid & 1;

    int ebase[3];
#pragma unroll
    for (int t = 0; t < 3; ++t) {
        int m  = t * 16 + lr;
        int yl = m / 24;
        int xx = m - yl * 24;
        ebase[t] = ((2 * prow + yl) * 26 + xx) * ICP + quad * 8;
    }

    f32x4 acc[3][2];
#pragma unroll
    for (int t = 0; t < 3; ++t)
#pragma unroll
        for (int n = 0; n < 2; ++n) acc[t][n] = (f32x4){0.f, 0.f, 0.f, 0.f};

    const ushort_t* wb = wr + (size_t)(nhalf * 32 + lr) * 288 + quad * 8;

#pragma unroll
    for (int tap = 0; tap < 9; ++tap) {
        int ky = tap / 3, kx = tap % 3;
        int koff = (ky * 26 + kx) * ICP;
        s16x8 a[3];
#pragma unroll
        for (int t = 0; t < 3; ++t) {
            union { ushort4v s[2]; s16x8 v; } u;
            u.s[0] = *reinterpret_cast<const ushort4v*>(&lds[ebase[t] + koff]);
            u.s[1] = *reinterpret_cast<const ushort4v*>(&lds[ebase[t] + koff + 4]);
            a[t] = u.v;
        }
        s16x8 bf[2];
#pragma unroll
        for (int n = 0; n < 2; ++n)
            bf[n] = *reinterpret_cast<const s16x8*>(wb + (size_t)n * 16 * 288 + tap * 32);
#pragma unroll
        for (int t = 0; t < 3; ++t)
#pragma unroll
            for (int n = 0; n < 2; ++n)
                acc[t][n] = __builtin_amdgcn_mfma_f32_16x16x32_bf16(a[t], bf[n], acc[t][n], 0, 0, 0);
    }
    __syncthreads();

    ushort_t* scr = lds + wid * (32 * SCR);
#pragma unroll
    for (int t = 0; t < 3; ++t)
#pragma unroll
        for (int n = 0; n < 2; ++n) {
            int ocl = n * 16 + lr;
            int i0 = t * 8 + quad * 2;
            float v0 = fmaxf(acc[t][n][0], acc[t][n][1]);
            float v1 = fmaxf(acc[t][n][2], acc[t][n][3]);
            union { ushort_t u2[2]; unsigned w; } pk;
            pk.u2[0] = f2bf(v0); pk.u2[1] = f2bf(v1);
            *reinterpret_cast<unsigned*>(&scr[ocl * SCR + i0]) = pk.w;
        }
    int ocl = lane & 31;
    int pxh = lane >> 5;
    int oc  = nhalf * 32 + ocl;
    const ushort_t* row = scr + ocl * SCR;
    float bv = bias[oc];
    int py = c * 4 + prow;
    ushort_t* po = pool2cl + ((size_t)b * 144 + py * 12) * 64 + oc;
#pragma unroll
    for (int j = 0; j < 6; ++j) {
        int px = pxh * 6 + j;
        float r0 = bf2f(row[px]);
        float r1 = bf2f(row[px + 12]);
        po[px * 64] = f2bf(fmaxf(fmaxf(r0, r1) + bv, 0.0f));
    }
}

// ---------------- k3: fc1 bf16 MFMA, 16 K-splits (R12 form) ----------------
__global__ __launch_bounds__(256) void fc1_mfma(const ushort_t* __restrict__ A,
                                                 const ushort_t* __restrict__ W,
                                                 float* __restrict__ Cpart) {
    int tid = threadIdx.x;
    int lane = tid & 63, wid = tid >> 6;
    int lr = lane & 15, quad = lane >> 4;
    int w  = blockIdx.x * 4 + wid;
    int nt = w & 3;
    int ks = (w >> 2) & 15;
    int mt = w >> 6;

    int m0 = mt * 16;
    int n0 = nt * 32;
    int k0 = ks * 576 + quad * 8;
    const ushort_t* a0 = A + (size_t)(m0 + lr) * 9216 + k0;
    const ushort_t* b0 = W + (size_t)(n0 + lr) * 9216 + k0;
    const ushort_t* b1 = b0 + (size_t)16 * 9216;

    f32x4 acc0 = (f32x4){0.f, 0.f, 0.f, 0.f};
    f32x4 acc1 = (f32x4){0.f, 0.f, 0.f, 0.f};

#pragma unroll
    for (int kk = 0; kk < 18; ++kk) {
        s16x8 av  = *reinterpret_cast<const s16x8*>(a0 + kk * 32);
        s16x8 bv0 = *reinterpret_cast<const s16x8*>(b0 + kk * 32);
        s16x8 bv1 = *reinterpret_cast<const s16x8*>(b1 + kk * 32);
        acc0 = __builtin_amdgcn_mfma_f32_16x16x32_bf16(av, bv0, acc0, 0, 0, 0);
        acc1 = __builtin_amdgcn_mfma_f32_16x16x32_bf16(av, bv1, acc1, 0, 0, 0);
    }

    float* cp = Cpart + (size_t)ks * (512 * 128);
    int crow = m0 + quad * 4;
#pragma unroll
    for (int r = 0; r < 4; ++r) {
        cp[(size_t)(crow + r) * 128 + n0 + lr]      = acc0[r];
        cp[(size_t)(crow + r) * 128 + n0 + 16 + lr] = acc1[r];
    }
}

// ---------------- k4: fc1 reduce(16) + bias + relu + fc2 (R12 form) ----------------
__global__ __launch_bounds__(256) void fc1fc2(const float* __restrict__ Cpart,
                                              const float* __restrict__ b1,
                                              const float* __restrict__ w2,
                                              const float* __restrict__ b2,
                                              float* __restrict__ out) {
    __shared__ float h[2][128];
    int half = threadIdx.x >> 7;
    int k = threadIdx.x & 127;
    int b = blockIdx.x * 2 + half;
    float s = 0.f;
#pragma unroll
    for (int ks = 0; ks < 16; ++ks) s += Cpart[(size_t)ks * (512 * 128) + b * 128 + k];
    h[half][k] = fmaxf(s + b1[k], 0.0f);
    __syncthreads();
    if (k < 10) {
        const float* wp = w2 + k * 128;
        float acc = 0.f;
#pragma unroll 8
        for (int j = 0; j < 128; ++j) acc += h[half][j] * wp[j];
        out[b * 10 + k] = acc + b2[k];
    }
}

extern "C" void kernel_launch(void* const* d_in, const int* in_sizes, int n_in,
                              void* d_out, int out_size, void* d_ws, size_t ws_size,
                              hipStream_t stream) {
    const float* x       = (const float*)d_in[0];
    const float* conv1_w = (const float*)d_in[1];
    const float* conv1_b = (const float*)d_in[2];
    const float* conv2_w = (const float*)d_in[3];
    const float* conv2_b = (const float*)d_in[4];
    const float* fc1_w   = (const float*)d_in[5];
    const float* fc1_b   = (const float*)d_in[6];
    const float* fc2_w   = (const float*)d_in[7];
    const float* fc2_b   = (const float*)d_in[8];
    float* out = (float*)d_out;

    char* ws = (char*)d_ws;
    ushort_t* pool1 = (ushort_t*)ws;
    ws += (size_t)B * POS * 32 * sizeof(ushort_t);
    ushort_t* wr = (ushort_t*)ws;
    ws += N_WR * sizeof(ushort_t) + 128;
    ushort_t* wfb = (ushort_t*)ws;
    ws += (size_t)128 * 9216 * sizeof(ushort_t) + 128;
    ushort_t* pool2cl = (ushort_t*)ws;
    ws += (size_t)B * P2SZ * sizeof(ushort_t) + 128;
    float* Cpart = (float*)ws;
    ws += (size_t)16 * 512 * 128 * sizeof(float) + 128;

    conv1_prep<<<CONV1_BLOCKS + WR_BLOCKS + TR_BLOCKS, 256, 0, stream>>>(
        x, conv1_w, conv1_b, conv2_w, fc1_w, pool1, wr, wfb);
    conv2_mfma<<<B * 3, 512, 0, stream>>>(pool1, wr, conv2_b, pool2cl);
    fc1_mfma<<<512, 256, 0, stream>>>(pool2cl, wfb, Cpart);
    fc1fc2<<<256, 256, 0, stream>>>(Cpart, fc1_b, fc2_w, fc2_b, out);
}